// Round 4
// baseline (345.369 us; speedup 1.0000x reference)
//
#include <hip/hip_runtime.h>
#include <math.h>

#define N_TOK   16384
#define K_TOT   (8 * N_TOK)      // 131072 reduction rows per batch
#define N_BATCH 4
#define BPB     128              // K1 blocks per batch
#define RPB     (K_TOT / BPB)    // 1024 contiguous rows per block
#define RPW     (RPB / 8)        // 128 contiguous rows per wave
#define BR      8                // rows per wave-buffer
#define NB      (RPW / BR)       // 16 buffers per wave

typedef const __attribute__((address_space(1))) unsigned int* as1_u32p;
typedef __attribute__((address_space(3))) unsigned int* as3_u32p;

__device__ __forceinline__ void gload16(const float* g, float* l) {
  __builtin_amdgcn_global_load_lds((as1_u32p)g, (as3_u32p)l, 16, 0, 0);
}

// s_waitcnt simm16: vmcnt[3:0]=b3:0, expcnt=b6:4, lgkmcnt=b11:8, vmcnt[5:4]=b15:14
#define WAITCNT_VM4  0x0F74   // vmcnt(4), lgkm/exp unconstrained
#define WAITCNT_VM0  0x0F70   // vmcnt(0)

// ---------------------------------------------------------------------------
// K1: partial kv accumulation, BARRIER-FREE K-loop. grid = 512 x 512 thr.
// Each wave owns 128 contiguous rows and a PRIVATE 8 KiB LDS double buffer
// staged via global_load_lds; sync is per-wave s_waitcnt vmcnt(4) only (the
// prefetched buffer's 4 loads stay in flight). No __syncthreads until the
// final 8-wave reduce -> waves stall independently, not in lockstep.
// ---------------------------------------------------------------------------
__global__ __launch_bounds__(512, 4) void k1_accum(
    const float* __restrict__ key, const float* __restrict__ val,
    float* __restrict__ part) {
  __shared__ float lds[16384];   // 8 waves x 2048 floats private
  int blk  = blockIdx.x;
  int b    = blk / BPB;
  int p    = blk % BPB;
  int wave = threadIdx.x >> 6;
  int lane = threadIdx.x & 63;
  int i = lane >> 3;             // c-octet
  int j = lane & 7;              // d-octet

  size_t row0 = (size_t)b * K_TOT + (size_t)p * RPB + (size_t)wave * RPW;
  const float* kb = key + row0 * 64;
  const float* vb = val + row0 * 64;
  float* wl = &lds[wave * 2048]; // wave-private: [2 bufs][key 512 | val 512]

  float acc[8][8];
#pragma unroll
  for (int a = 0; a < 8; a++)
#pragma unroll
    for (int c = 0; c < 8; c++) acc[a][c] = 0.f;

  // stage buffer t (8 rows = 2 KiB key + 2 KiB val) into slot s: 4 gloads
  {
    const float* kg = kb;
    const float* vg = vb;
    gload16(kg + lane * 4,       wl);
    gload16(kg + 256 + lane * 4, wl + 256);
    gload16(vg + lane * 4,       wl + 512);
    gload16(vg + 256 + lane * 4, wl + 768);
  }

  for (int t = 0; t < NB; t++) {
    if (t + 1 < NB) {
      const float* kg = kb + (size_t)(t + 1) * (BR * 64);
      const float* vg = vb + (size_t)(t + 1) * (BR * 64);
      float* d = wl + ((t + 1) & 1) * 1024;
      gload16(kg + lane * 4,       d);
      gload16(kg + 256 + lane * 4, d + 256);
      gload16(vg + lane * 4,       d + 512);
      gload16(vg + 256 + lane * 4, d + 768);
      __builtin_amdgcn_s_waitcnt(WAITCNT_VM4);  // buf t done; t+1 in flight
    } else {
      __builtin_amdgcn_s_waitcnt(WAITCNT_VM0);
    }
    asm volatile("" ::: "memory");              // pin ds_reads below waitcnt

    const float* ks = wl + (t & 1) * 1024;
    const float* vs = ks + 512;
#pragma unroll
    for (int rr = 0; rr < BR; rr++) {
      float4 k0 = *(const float4*)&ks[rr * 64 + 8 * i];
      float4 k1 = *(const float4*)&ks[rr * 64 + 8 * i + 4];
      float4 v0 = *(const float4*)&vs[rr * 64 + 8 * j];
      float4 v1 = *(const float4*)&vs[rr * 64 + 8 * j + 4];
      float kr[8] = {k0.x, k0.y, k0.z, k0.w, k1.x, k1.y, k1.z, k1.w};
      float vr[8] = {v0.x, v0.y, v0.z, v0.w, v1.x, v1.y, v1.z, v1.w};
#pragma unroll
      for (int a = 0; a < 8; a++)
#pragma unroll
        for (int c = 0; c < 8; c++)
          acc[a][c] = fmaf(kr[a], vr[c], acc[a][c]);
    }
    asm volatile("" ::: "memory");              // pin next stage after reads
  }

  // --- 8-wave reduce (aliases private regions; all waves drained by barrier) ---
  __syncthreads();
  float (*red)[4096] = (float(*)[4096])lds;
  if (wave < 2) {
#pragma unroll
    for (int a = 0; a < 8; a++) {
      int c = 8 * i + a;
      *(float4*)&red[wave][c * 64 + 8 * j] =
          make_float4(acc[a][0], acc[a][1], acc[a][2], acc[a][3]);
      *(float4*)&red[wave][c * 64 + 8 * j + 4] =
          make_float4(acc[a][4], acc[a][5], acc[a][6], acc[a][7]);
    }
  }
  __syncthreads();
#pragma unroll
  for (int g = 1; g < 4; g++) {
    if (wave >= 2 * g && wave < 2 * g + 2) {
      int wb = wave - 2 * g;
#pragma unroll
      for (int a = 0; a < 8; a++) {
        int c = 8 * i + a;
        float4* d0 = (float4*)&red[wb][c * 64 + 8 * j];
        float4* d1 = (float4*)&red[wb][c * 64 + 8 * j + 4];
        float4 x0 = *d0, x1 = *d1;
        *d0 = make_float4(x0.x + acc[a][0], x0.y + acc[a][1],
                          x0.z + acc[a][2], x0.w + acc[a][3]);
        *d1 = make_float4(x1.x + acc[a][4], x1.y + acc[a][5],
                          x1.z + acc[a][6], x1.w + acc[a][7]);
      }
    }
    __syncthreads();
  }

  float* dst = part + (size_t)blk * 4096;
  int t = threadIdx.x;
#pragma unroll
  for (int x = 0; x < 8; x++) {
    int e = t + 512 * x;
    dst[e] = red[0][e] + red[1][e];
  }
}

// ---------------------------------------------------------------------------
// K2: reduce 128 partial tiles per batch -> kv[b][c][d].
// ---------------------------------------------------------------------------
__global__ __launch_bounds__(256, 4) void k2_reduce(
    const float* __restrict__ part, float* __restrict__ kv, int bpb) {
  int b  = blockIdx.x >> 6;
  int c  = blockIdx.x & 63;
  int p4 = threadIdx.x >> 6;
  int d  = threadIdx.x & 63;

  float s = 0.f;
  int iters = bpb >> 2;
  const float* src = part + (size_t)(b * bpb) * 4096 + c * 64 + d;
#pragma unroll 4
  for (int x = 0; x < iters; x++) s += src[(size_t)(p4 + 4 * x) * 4096];

  __shared__ float l[256];
  l[threadIdx.x] = s;
  __syncthreads();
  if (p4 == 0)
    kv[((size_t)b * 64 + c) * 64 + d] = l[d] + l[64 + d] + l[128 + d] + l[192 + d];
}

// ---------------------------------------------------------------------------
// K2b: softmax over C (axis=1) -> P[b][c][d]. grid = 4 blocks, 64 threads.
// ---------------------------------------------------------------------------
__global__ __launch_bounds__(64, 1) void k2b_softmax(
    const float* __restrict__ kv, float* __restrict__ P) {
  int b = blockIdx.x;
  int d = threadIdx.x;
  const float* s = kv + (size_t)b * 4096 + d;
  float v[64];
#pragma unroll
  for (int c = 0; c < 64; c++) v[c] = s[c * 64];
  float mx = v[0];
#pragma unroll
  for (int c = 1; c < 64; c++) mx = fmaxf(mx, v[c]);
  float sum = 0.f;
#pragma unroll
  for (int c = 0; c < 64; c++) {
    v[c] = __expf(v[c] - mx);
    sum += v[c];
  }
  float inv = 1.f / sum;
  float* o = P + (size_t)b * 4096 + d;
#pragma unroll
  for (int c = 0; c < 64; c++) o[c * 64] = v[c] * inv;
}

// ---------------------------------------------------------------------------
// K3: out[b,m,d] = alpha * sum_c key_cur[b,m,c]*P[c,d] + val_cur[b,m,d].
// ---------------------------------------------------------------------------
__global__ __launch_bounds__(256, 4) void k3_out(
    const float* __restrict__ P, const float* __restrict__ keyc,
    const float* __restrict__ valc, const float* __restrict__ alphap,
    float* __restrict__ out) {
  __shared__ float Ps[4096];
  __shared__ float kT[64 * 68];

  int bb = blockIdx.x >> 8;
  int mb = blockIdx.x & 255;
  int m0 = mb * 64;
  int t = threadIdx.x;

  const float4* p4 = (const float4*)(P + (size_t)bb * 4096);
  float4* ps4 = (float4*)Ps;
#pragma unroll
  for (int u = 0; u < 4; u++) ps4[t + 256 * u] = p4[t + 256 * u];

  int r  = t >> 2;
  int cb = (t & 3) * 16;
  const float* krow = keyc + ((size_t)bb * N_TOK + m0 + r) * 64;
#pragma unroll
  for (int u = 0; u < 4; u++) {
    float4 kk = *(const float4*)&krow[cb + 4 * u];
    int c = cb + 4 * u;
    kT[(c + 0) * 68 + r] = kk.x;
    kT[(c + 1) * 68 + r] = kk.y;
    kT[(c + 2) * 68 + r] = kk.z;
    kT[(c + 3) * 68 + r] = kk.w;
  }
  __syncthreads();

  int wave = t >> 6, lane = t & 63;
  int mi = lane >> 3, j = lane & 7;
  int m = wave * 16 + mi * 2;

  float acc[2][8];
#pragma unroll
  for (int a = 0; a < 2; a++)
#pragma unroll
    for (int d = 0; d < 8; d++) acc[a][d] = 0.f;

#pragma unroll 4
  for (int c = 0; c < 64; c++) {
    float2 kk = *(const float2*)&kT[c * 68 + m];
    float4 p0 = *(const float4*)&Ps[c * 64 + 8 * j];
    float4 p1 = *(const float4*)&Ps[c * 64 + 8 * j + 4];
    float pr[8] = {p0.x, p0.y, p0.z, p0.w, p1.x, p1.y, p1.z, p1.w};
#pragma unroll
    for (int d = 0; d < 8; d++) {
      acc[0][d] = fmaf(kk.x, pr[d], acc[0][d]);
      acc[1][d] = fmaf(kk.y, pr[d], acc[1][d]);
    }
  }

  float alpha = alphap[0];
#pragma unroll
  for (int a = 0; a < 2; a++) {
    size_t off = ((size_t)bb * N_TOK + m0 + m + a) * 64 + 8 * j;
    float4 v0 = *(const float4*)&valc[off];
    float4 v1 = *(const float4*)&valc[off + 4];
    float4 o0 = make_float4(fmaf(alpha, acc[a][0], v0.x),
                            fmaf(alpha, acc[a][1], v0.y),
                            fmaf(alpha, acc[a][2], v0.z),
                            fmaf(alpha, acc[a][3], v0.w));
    float4 o1 = make_float4(fmaf(alpha, acc[a][4], v1.x),
                            fmaf(alpha, acc[a][5], v1.y),
                            fmaf(alpha, acc[a][6], v1.z),
                            fmaf(alpha, acc[a][7], v1.w));
    *(float4*)&out[off] = o0;
    *(float4*)&out[off + 4] = o1;
  }
}

// ---------------------------------------------------------------------------
extern "C" void kernel_launch(void* const* d_in, const int* in_sizes, int n_in,
                              void* d_out, int out_size, void* d_ws,
                              size_t ws_size, hipStream_t stream) {
  const float* key_mem = (const float*)d_in[0];
  const float* val_mem = (const float*)d_in[1];
  const float* key_cur = (const float*)d_in[2];
  const float* val_cur = (const float*)d_in[3];
  const float* alpha   = (const float*)d_in[4];
  float* out = (float*)d_out;
  float* ws  = (float*)d_ws;

  float* part = ws;                                    // 512 tiles (8.4 MB)
  float* kv   = ws + (size_t)(N_BATCH * BPB) * 4096;   // 4 tiles
  float* P    = ws;                                    // aliases consumed part

  k1_accum<<<N_BATCH * BPB, 512, 0, stream>>>(key_mem, val_mem, part);
  k2_reduce<<<256, 256, 0, stream>>>(part, kv, BPB);
  k2b_softmax<<<N_BATCH, 64, 0, stream>>>(kv, P);
  k3_out<<<N_BATCH * (N_TOK / 64), 256, 0, stream>>>(P, key_cur, val_cur,
                                                     alpha, out);
}

// Round 5
// 322.317 us; speedup vs baseline: 1.0715x; 1.0715x over previous
//
#include <hip/hip_runtime.h>
#include <math.h>

#define N_TOK   16384
#define K_TOT   (8 * N_TOK)      // 131072 reduction rows per batch
#define N_BATCH 4
#define BPB     128              // K1 blocks per batch
#define RPB     (K_TOT / BPB)    // 1024 contiguous rows per block
#define CHUNK   64               // rows per LDS chunk
#define NCH     (RPB / CHUNK)    // 16 chunks per block
#define PITCH_U 36               // uints per LDS row (72 bf16 = 144 B, 16B-aligned)
#define PART_U  (64 * PITCH_U)   // 2304 uints per part (Ah/Al/Vh/Vl)

typedef short short8 __attribute__((ext_vector_type(8)));
typedef float f32x4  __attribute__((ext_vector_type(4)));

union FragU { uint4 u; short8 s; };

// RNE round fp32 -> bf16 (top 16 bits)
__device__ __forceinline__ uint bf16_rne(float f, float* rounded) {
  uint u = __float_as_uint(f);
  uint r = u + 0x7FFFu + ((u >> 16) & 1u);
  *rounded = __uint_as_float(r & 0xFFFF0000u);
  return r >> 16;
}

// ---------------------------------------------------------------------------
// K1: kv partial tiles via MFMA bf16 hi/lo split (3 passes: hh + hl + lh).
// grid = 512 blocks x 512 thr (8 waves). Per chunk (64 rows):
//  - stage: threads load float4 rows (1 KiB/instr coalesced), split hi/lo
//    (RNE), write TRANSPOSED bf16 tiles At[c][k], Vt[d][k] (pitch 72).
//  - compute: 8 waves x 2 (16x16) tiles each; frags via single ds_read_b128;
//    3 MFMAs per (tile,kstep). Tiles wave-owned -> no cross-wave reduce.
// 2-barrier chunk loop (m97 structure); global loads for chunk t+1 issued
// before compute(t) so their latency hides under MFMA + other block.
// ---------------------------------------------------------------------------
__global__ __launch_bounds__(512, 2) void k1_mfma(
    const float* __restrict__ key, const float* __restrict__ val,
    float* __restrict__ part) {
  __shared__ uint lds[4 * PART_U];   // 36,864 B: [Ah | Al | Vh | Vl]

  int blk  = blockIdx.x;
  int b    = blk / BPB;
  int p    = blk % BPB;
  int t    = threadIdx.x;
  int wave = t >> 6;
  int lane = t & 63;

  // staging role: waves 0-3 -> key, 4-7 -> val; 4x4 element block per thread
  int arr = t >> 8;                  // 0 = key, 1 = val
  int tt  = t & 255;
  int c0  = (tt & 15) * 4;           // 4 consecutive channels
  int r0  = (tt >> 4) * 4;           // 4 consecutive rows
  const float* src = arr ? val : key;
  size_t rowbase = (size_t)b * K_TOT + (size_t)p * RPB;
  uint sbase = arr * 2 * PART_U;     // key -> parts 0/1, val -> parts 2/3

  // compute role: wave -> (mt, 2 n-tiles)
  int mt  = wave >> 1;               // 0..3
  int ntb = (wave & 1) * 2;          // 0 or 2
  int m16 = lane & 15;
  int ko  = lane >> 4;               // k-octet 0..3

  f32x4 acc[2] = {{0.f, 0.f, 0.f, 0.f}, {0.f, 0.f, 0.f, 0.f}};
  float4 ld[4];

  auto load_chunk = [&](int ch) {
#pragma unroll
    for (int q = 0; q < 4; q++)
      ld[q] = *(const float4*)&src[(rowbase + (size_t)ch * CHUNK + r0 + q) * 64 + c0];
  };

  auto write_chunk = [&]() {
#pragma unroll
    for (int cc = 0; cc < 4; cc++) {
      uint h[4], l[4];
#pragma unroll
      for (int q = 0; q < 4; q++) {
        float f = (&ld[q].x)[cc];
        float hf;
        h[q] = bf16_rne(f, &hf);
        float dummy;
        l[q] = bf16_rne(f - hf, &dummy);
      }
      uint2 hp = make_uint2(h[0] | (h[1] << 16), h[2] | (h[3] << 16));
      uint2 lp = make_uint2(l[0] | (l[1] << 16), l[2] | (l[3] << 16));
      uint base = sbase + (uint)(c0 + cc) * PITCH_U + (uint)(r0 >> 1);
      *(uint2*)&lds[base]          = hp;
      *(uint2*)&lds[base + PART_U] = lp;
    }
  };

  load_chunk(0);
  write_chunk();
  __syncthreads();

  for (int ch = 0; ch < NCH; ch++) {
    if (ch + 1 < NCH) load_chunk(ch + 1);

    // compute on LDS chunk ch
#pragma unroll
    for (int ks = 0; ks < 2; ks++) {
      uint ao = (uint)(mt * 16 + m16) * PITCH_U + ks * 16 + ko * 4;
      FragU Ah, Al;
      Ah.u = *(const uint4*)&lds[ao];
      Al.u = *(const uint4*)&lds[ao + PART_U];
#pragma unroll
      for (int nn = 0; nn < 2; nn++) {
        uint bo = 2 * PART_U + (uint)((ntb + nn) * 16 + m16) * PITCH_U + ks * 16 + ko * 4;
        FragU Bh, Bl;
        Bh.u = *(const uint4*)&lds[bo];
        Bl.u = *(const uint4*)&lds[bo + PART_U];
        acc[nn] = __builtin_amdgcn_mfma_f32_16x16x32_bf16(Ah.s, Bh.s, acc[nn], 0, 0, 0);
        acc[nn] = __builtin_amdgcn_mfma_f32_16x16x32_bf16(Ah.s, Bl.s, acc[nn], 0, 0, 0);
        acc[nn] = __builtin_amdgcn_mfma_f32_16x16x32_bf16(Al.s, Bh.s, acc[nn], 0, 0, 0);
      }
    }
    __syncthreads();                 // all frag reads of this chunk done
    if (ch + 1 < NCH) write_chunk(); // overwrite LDS with chunk ch+1
    __syncthreads();
  }

  // epilogue: D layout col=lane&15, row=(lane>>4)*4+reg [m89-verified]
  float* dst = part + (size_t)blk * 4096;
#pragma unroll
  for (int nn = 0; nn < 2; nn++) {
    int d = (ntb + nn) * 16 + m16;
#pragma unroll
    for (int r = 0; r < 4; r++) {
      int c = mt * 16 + ko * 4 + r;
      dst[c * 64 + d] = acc[nn][r];
    }
  }
}

// ---------------------------------------------------------------------------
// K2: reduce 128 partial tiles per batch -> kv[b][c][d].
// ---------------------------------------------------------------------------
__global__ __launch_bounds__(256, 4) void k2_reduce(
    const float* __restrict__ part, float* __restrict__ kv, int bpb) {
  int b  = blockIdx.x >> 6;
  int c  = blockIdx.x & 63;
  int p4 = threadIdx.x >> 6;
  int d  = threadIdx.x & 63;

  float s = 0.f;
  int iters = bpb >> 2;
  const float* src = part + (size_t)(b * bpb) * 4096 + c * 64 + d;
#pragma unroll 4
  for (int x = 0; x < iters; x++) s += src[(size_t)(p4 + 4 * x) * 4096];

  __shared__ float l[256];
  l[threadIdx.x] = s;
  __syncthreads();
  if (p4 == 0)
    kv[((size_t)b * 64 + c) * 64 + d] = l[d] + l[64 + d] + l[128 + d] + l[192 + d];
}

// ---------------------------------------------------------------------------
// K2b: softmax over C (axis=1) -> P[b][c][d]. grid = 256 blocks (b,d),
// 64 threads = c; butterfly shuffle reductions.
// ---------------------------------------------------------------------------
__global__ __launch_bounds__(64, 4) void k2b_softmax(
    const float* __restrict__ kv, float* __restrict__ P) {
  int b = blockIdx.x >> 6;
  int d = blockIdx.x & 63;
  int c = threadIdx.x;
  float v = kv[(size_t)b * 4096 + c * 64 + d];
  float mx = v;
#pragma unroll
  for (int o = 32; o; o >>= 1) mx = fmaxf(mx, __shfl_xor(mx, o, 64));
  float e = __expf(v - mx);
  float s = e;
#pragma unroll
  for (int o = 32; o; o >>= 1) s += __shfl_xor(s, o, 64);
  P[(size_t)b * 4096 + c * 64 + d] = e / s;
}

// ---------------------------------------------------------------------------
// K3: out[b,m,d] = alpha * sum_c key_cur[b,m,c]*P[c,d] + val_cur[b,m,d].
// ---------------------------------------------------------------------------
__global__ __launch_bounds__(256, 4) void k3_out(
    const float* __restrict__ P, const float* __restrict__ keyc,
    const float* __restrict__ valc, const float* __restrict__ alphap,
    float* __restrict__ out) {
  __shared__ float Ps[4096];
  __shared__ float kT[64 * 68];

  int bb = blockIdx.x >> 8;
  int mb = blockIdx.x & 255;
  int m0 = mb * 64;
  int t = threadIdx.x;

  const float4* p4 = (const float4*)(P + (size_t)bb * 4096);
  float4* ps4 = (float4*)Ps;
#pragma unroll
  for (int u = 0; u < 4; u++) ps4[t + 256 * u] = p4[t + 256 * u];

  int r  = t >> 2;
  int cb = (t & 3) * 16;
  const float* krow = keyc + ((size_t)bb * N_TOK + m0 + r) * 64;
#pragma unroll
  for (int u = 0; u < 4; u++) {
    float4 kk = *(const float4*)&krow[cb + 4 * u];
    int c = cb + 4 * u;
    kT[(c + 0) * 68 + r] = kk.x;
    kT[(c + 1) * 68 + r] = kk.y;
    kT[(c + 2) * 68 + r] = kk.z;
    kT[(c + 3) * 68 + r] = kk.w;
  }
  __syncthreads();

  int wave = t >> 6, lane = t & 63;
  int mi = lane >> 3, j = lane & 7;
  int m = wave * 16 + mi * 2;

  float acc[2][8];
#pragma unroll
  for (int a = 0; a < 2; a++)
#pragma unroll
    for (int d = 0; d < 8; d++) acc[a][d] = 0.f;

#pragma unroll 4
  for (int c = 0; c < 64; c++) {
    float2 kk = *(const float2*)&kT[c * 68 + m];
    float4 p0 = *(const float4*)&Ps[c * 64 + 8 * j];
    float4 p1 = *(const float4*)&Ps[c * 64 + 8 * j + 4];
    float pr[8] = {p0.x, p0.y, p0.z, p0.w, p1.x, p1.y, p1.z, p1.w};
#pragma unroll
    for (int d = 0; d < 8; d++) {
      acc[0][d] = fmaf(kk.x, pr[d], acc[0][d]);
      acc[1][d] = fmaf(kk.y, pr[d], acc[1][d]);
    }
  }

  float alpha = alphap[0];
#pragma unroll
  for (int a = 0; a < 2; a++) {
    size_t off = ((size_t)bb * N_TOK + m0 + m + a) * 64 + 8 * j;
    float4 v0 = *(const float4*)&valc[off];
    float4 v1 = *(const float4*)&valc[off + 4];
    float4 o0 = make_float4(fmaf(alpha, acc[a][0], v0.x),
                            fmaf(alpha, acc[a][1], v0.y),
                            fmaf(alpha, acc[a][2], v0.z),
                            fmaf(alpha, acc[a][3], v0.w));
    float4 o1 = make_float4(fmaf(alpha, acc[a][4], v1.x),
                            fmaf(alpha, acc[a][5], v1.y),
                            fmaf(alpha, acc[a][6], v1.z),
                            fmaf(alpha, acc[a][7], v1.w));
    *(float4*)&out[off] = o0;
    *(float4*)&out[off + 4] = o1;
  }
}

// ---------------------------------------------------------------------------
extern "C" void kernel_launch(void* const* d_in, const int* in_sizes, int n_in,
                              void* d_out, int out_size, void* d_ws,
                              size_t ws_size, hipStream_t stream) {
  const float* key_mem = (const float*)d_in[0];
  const float* val_mem = (const float*)d_in[1];
  const float* key_cur = (const float*)d_in[2];
  const float* val_cur = (const float*)d_in[3];
  const float* alpha   = (const float*)d_in[4];
  float* out = (float*)d_out;
  float* ws  = (float*)d_ws;

  float* part = ws;                                    // 512 tiles (8.4 MB)
  float* kv   = ws + (size_t)(N_BATCH * BPB) * 4096;   // 4 tiles
  float* P    = ws;                                    // aliases consumed part

  k1_mfma<<<N_BATCH * BPB, 512, 0, stream>>>(key_mem, val_mem, part);
  k2_reduce<<<256, 256, 0, stream>>>(part, kv, BPB);
  k2b_softmax<<<N_BATCH * 64, 64, 0, stream>>>(kv, P);
  k3_out<<<N_BATCH * (N_TOK / 64), 256, 0, stream>>>(P, key_cur, val_cur,
                                                     alpha, out);
}

// Round 6
// 319.579 us; speedup vs baseline: 1.0807x; 1.0086x over previous
//
#include <hip/hip_runtime.h>
#include <math.h>

#define N_TOK   16384
#define K_TOT   (8 * N_TOK)      // 131072 reduction rows per batch
#define N_BATCH 4
#define BPB     128              // K1 blocks per batch
#define RPB     (K_TOT / BPB)    // 1024 contiguous rows per block
#define CHUNK   64               // rows per LDS chunk
#define NCH     (RPB / CHUNK)    // 16 chunks per block
#define PITCH_U 36               // uints per LDS row (72 bf16, 16B-aligned)
#define PART_U  (64 * PITCH_U)   // 2304 uints per part (Ah/Al/Vh/Vl)

typedef short short8 __attribute__((ext_vector_type(8)));
typedef float f32x4  __attribute__((ext_vector_type(4)));

union FragU { uint4 u; short8 s; };

// RNE round fp32 -> bf16 (top 16 bits)
__device__ __forceinline__ uint bf16_rne(float f, float* rounded) {
  uint u = __float_as_uint(f);
  uint r = u + 0x7FFFu + ((u >> 16) & 1u);
  *rounded = __uint_as_float(r & 0xFFFF0000u);
  return r >> 16;
}

// barrier WITHOUT vmcnt drain: only lgkmcnt(0) (LDS visibility), then s_barrier.
// 0xC07F = vmcnt(63 = no wait) | expcnt(7 = no wait) | lgkmcnt(0).
__device__ __forceinline__ void barrier_nodrain() {
  asm volatile("" ::: "memory");
  __builtin_amdgcn_s_waitcnt(0xC07F);
  __builtin_amdgcn_s_barrier();
  asm volatile("" ::: "memory");
}

// ---------------------------------------------------------------------------
// K1: kv partials via MFMA bf16 hi/lo split. grid = 512 x 512 thr (8 waves).
// STREAMING K-loop: depth-2 register pipeline (chunks t+1,t+2 in flight) +
// dual LDS chunk buffers + raw s_barrier with NO vmcnt drain -> global loads
// outstanding continuously (HBM duty cycle ~100%, vs ~40% with __syncthreads'
// mandatory vmcnt(0)). One barrier per chunk:
//   issue loads(t+2) | compute(t) from LDS[t&1] | write regs(t+1)->LDS[(t+1)&1]
//   | lgkm-drain + s_barrier.
// compute(t) reads and write(t+1) writes DIFFERENT buffers; cross-iteration
// hazards are covered by the single barrier.
// ---------------------------------------------------------------------------
__global__ __launch_bounds__(512, 2) void k1_mfma(
    const float* __restrict__ key, const float* __restrict__ val,
    float* __restrict__ part) {
  __shared__ uint lds[2][4 * PART_U];   // 72 KiB: 2 x [Ah | Al | Vh | Vl]

  int blk  = blockIdx.x;
  int b    = blk / BPB;
  int p    = blk % BPB;
  int t    = threadIdx.x;
  int wave = t >> 6;
  int lane = t & 63;

  // staging role: threads 0-255 -> key, 256-511 -> val; 4x4 block per thread
  int arr = t >> 8;                  // 0 = key, 1 = val
  int tt  = t & 255;
  int c0  = (tt & 15) * 4;           // 4 consecutive channels
  int r0  = (tt >> 4) * 4;           // 4 consecutive rows
  const float* src = arr ? val : key;
  size_t rowbase = (size_t)b * K_TOT + (size_t)p * RPB;
  uint sbase = arr * 2 * PART_U;     // key -> parts 0/1, val -> parts 2/3

  // compute role: wave -> (m-tile, 2 n-tiles); 16x16x32 bf16 MFMA
  int mt  = wave >> 1;               // 0..3
  int ntb = (wave & 1) * 2;          // 0 or 2
  int m16 = lane & 15;
  int ko  = lane >> 4;               // k-octet 0..3

  f32x4 acc[2] = {{0.f, 0.f, 0.f, 0.f}, {0.f, 0.f, 0.f, 0.f}};
  float4 ld[2][4];                   // depth-2 pipeline registers

  auto load_chunk = [&](int ch, int par) {
#pragma unroll
    for (int q = 0; q < 4; q++)
      ld[par][q] =
          *(const float4*)&src[(rowbase + (size_t)ch * CHUNK + r0 + q) * 64 + c0];
  };

  auto write_chunk = [&](int par) {   // ld[par] -> lds[par], transposed hi/lo
#pragma unroll
    for (int cc = 0; cc < 4; cc++) {
      uint h[4], l[4];
#pragma unroll
      for (int q = 0; q < 4; q++) {
        float f = (&ld[par][q].x)[cc];
        float hf;
        h[q] = bf16_rne(f, &hf);
        float dummy;
        l[q] = bf16_rne(f - hf, &dummy);
      }
      uint2 hp = make_uint2(h[0] | (h[1] << 16), h[2] | (h[3] << 16));
      uint2 lp = make_uint2(l[0] | (l[1] << 16), l[2] | (l[3] << 16));
      uint base = sbase + (uint)(c0 + cc) * PITCH_U + (uint)(r0 >> 1);
      *(uint2*)&lds[par][base]          = hp;
      *(uint2*)&lds[par][base + PART_U] = lp;
    }
  };

  auto compute = [&](int par) {
#pragma unroll
    for (int ks = 0; ks < 2; ks++) {
      uint ao = (uint)(mt * 16 + m16) * PITCH_U + ks * 16 + ko * 4;
      FragU Ah, Al;
      Ah.u = *(const uint4*)&lds[par][ao];
      Al.u = *(const uint4*)&lds[par][ao + PART_U];
#pragma unroll
      for (int nn = 0; nn < 2; nn++) {
        uint bo = 2 * PART_U + (uint)((ntb + nn) * 16 + m16) * PITCH_U +
                  ks * 16 + ko * 4;
        FragU Bh, Bl;
        Bh.u = *(const uint4*)&lds[par][bo];
        Bl.u = *(const uint4*)&lds[par][bo + PART_U];
        acc[nn] = __builtin_amdgcn_mfma_f32_16x16x32_bf16(Ah.s, Bh.s, acc[nn], 0, 0, 0);
        acc[nn] = __builtin_amdgcn_mfma_f32_16x16x32_bf16(Ah.s, Bl.s, acc[nn], 0, 0, 0);
        acc[nn] = __builtin_amdgcn_mfma_f32_16x16x32_bf16(Al.s, Bh.s, acc[nn], 0, 0, 0);
      }
    }
  };

  // prologue: chunks 0 and 1 in flight; chunk 0 into LDS[0]
  load_chunk(0, 0);
  load_chunk(1, 1);
  write_chunk(0);          // compiler auto-waits vmcnt(4) for ld[0]
  barrier_nodrain();

#pragma unroll
  for (int ch = 0; ch < NCH; ch++) {
    if (ch + 2 < NCH) load_chunk(ch + 2, ch & 1);  // regs of chunk ch reusable
    compute(ch & 1);
    if (ch + 1 < NCH) write_chunk((ch + 1) & 1);   // auto vmcnt wait, t+2 stays in flight
    barrier_nodrain();
  }

  // epilogue: D layout col=lane&15, row=(lane>>4)*4+reg [m89-verified]
  float* dst = part + (size_t)blk * 4096;
#pragma unroll
  for (int nn = 0; nn < 2; nn++) {
    int d = (ntb + nn) * 16 + m16;
#pragma unroll
    for (int r = 0; r < 4; r++) {
      int c = mt * 16 + ko * 4 + r;
      dst[c * 64 + d] = acc[nn][r];
    }
  }
}

// ---------------------------------------------------------------------------
// K2: reduce 128 partial tiles per batch -> kv[b][c][d].
// ---------------------------------------------------------------------------
__global__ __launch_bounds__(256, 4) void k2_reduce(
    const float* __restrict__ part, float* __restrict__ kv, int bpb) {
  int b  = blockIdx.x >> 6;
  int c  = blockIdx.x & 63;
  int p4 = threadIdx.x >> 6;
  int d  = threadIdx.x & 63;

  float s = 0.f;
  int iters = bpb >> 2;
  const float* src = part + (size_t)(b * bpb) * 4096 + c * 64 + d;
#pragma unroll 4
  for (int x = 0; x < iters; x++) s += src[(size_t)(p4 + 4 * x) * 4096];

  __shared__ float l[256];
  l[threadIdx.x] = s;
  __syncthreads();
  if (p4 == 0)
    kv[((size_t)b * 64 + c) * 64 + d] = l[d] + l[64 + d] + l[128 + d] + l[192 + d];
}

// ---------------------------------------------------------------------------
// K2b: softmax over C (axis=1) -> P[b][c][d]. grid = 256 blocks (b,d),
// 64 threads = c; butterfly shuffle reductions.
// ---------------------------------------------------------------------------
__global__ __launch_bounds__(64, 4) void k2b_softmax(
    const float* __restrict__ kv, float* __restrict__ P) {
  int b = blockIdx.x >> 6;
  int d = blockIdx.x & 63;
  int c = threadIdx.x;
  float v = kv[(size_t)b * 4096 + c * 64 + d];
  float mx = v;
#pragma unroll
  for (int o = 32; o; o >>= 1) mx = fmaxf(mx, __shfl_xor(mx, o, 64));
  float e = __expf(v - mx);
  float s = e;
#pragma unroll
  for (int o = 32; o; o >>= 1) s += __shfl_xor(s, o, 64);
  P[(size_t)b * 4096 + c * 64 + d] = e / s;
}

// ---------------------------------------------------------------------------
// K3: out[b,m,d] = alpha * sum_c key_cur[b,m,c]*P[c,d] + val_cur[b,m,d].
// ---------------------------------------------------------------------------
__global__ __launch_bounds__(256, 4) void k3_out(
    const float* __restrict__ P, const float* __restrict__ keyc,
    const float* __restrict__ valc, const float* __restrict__ alphap,
    float* __restrict__ out) {
  __shared__ float Ps[4096];
  __shared__ float kT[64 * 68];

  int bb = blockIdx.x >> 8;
  int mb = blockIdx.x & 255;
  int m0 = mb * 64;
  int t = threadIdx.x;

  const float4* p4 = (const float4*)(P + (size_t)bb * 4096);
  float4* ps4 = (float4*)Ps;
#pragma unroll
  for (int u = 0; u < 4; u++) ps4[t + 256 * u] = p4[t + 256 * u];

  int r  = t >> 2;
  int cb = (t & 3) * 16;
  const float* krow = keyc + ((size_t)bb * N_TOK + m0 + r) * 64;
#pragma unroll
  for (int u = 0; u < 4; u++) {
    float4 kk = *(const float4*)&krow[cb + 4 * u];
    int c = cb + 4 * u;
    kT[(c + 0) * 68 + r] = kk.x;
    kT[(c + 1) * 68 + r] = kk.y;
    kT[(c + 2) * 68 + r] = kk.z;
    kT[(c + 3) * 68 + r] = kk.w;
  }
  __syncthreads();

  int wave = t >> 6, lane = t & 63;
  int mi = lane >> 3, j = lane & 7;
  int m = wave * 16 + mi * 2;

  float acc[2][8];
#pragma unroll
  for (int a = 0; a < 2; a++)
#pragma unroll
    for (int d = 0; d < 8; d++) acc[a][d] = 0.f;

#pragma unroll 4
  for (int c = 0; c < 64; c++) {
    float2 kk = *(const float2*)&kT[c * 68 + m];
    float4 p0 = *(const float4*)&Ps[c * 64 + 8 * j];
    float4 p1 = *(const float4*)&Ps[c * 64 + 8 * j + 4];
    float pr[8] = {p0.x, p0.y, p0.z, p0.w, p1.x, p1.y, p1.z, p1.w};
#pragma unroll
    for (int d = 0; d < 8; d++) {
      acc[0][d] = fmaf(kk.x, pr[d], acc[0][d]);
      acc[1][d] = fmaf(kk.y, pr[d], acc[1][d]);
    }
  }

  float alpha = alphap[0];
#pragma unroll
  for (int a = 0; a < 2; a++) {
    size_t off = ((size_t)bb * N_TOK + m0 + m + a) * 64 + 8 * j;
    float4 v0 = *(const float4*)&valc[off];
    float4 v1 = *(const float4*)&valc[off + 4];
    float4 o0 = make_float4(fmaf(alpha, acc[a][0], v0.x),
                            fmaf(alpha, acc[a][1], v0.y),
                            fmaf(alpha, acc[a][2], v0.z),
                            fmaf(alpha, acc[a][3], v0.w));
    float4 o1 = make_float4(fmaf(alpha, acc[a][4], v1.x),
                            fmaf(alpha, acc[a][5], v1.y),
                            fmaf(alpha, acc[a][6], v1.z),
                            fmaf(alpha, acc[a][7], v1.w));
    *(float4*)&out[off] = o0;
    *(float4*)&out[off + 4] = o1;
  }
}

// ---------------------------------------------------------------------------
extern "C" void kernel_launch(void* const* d_in, const int* in_sizes, int n_in,
                              void* d_out, int out_size, void* d_ws,
                              size_t ws_size, hipStream_t stream) {
  const float* key_mem = (const float*)d_in[0];
  const float* val_mem = (const float*)d_in[1];
  const float* key_cur = (const float*)d_in[2];
  const float* val_cur = (const float*)d_in[3];
  const float* alpha   = (const float*)d_in[4];
  float* out = (float*)d_out;
  float* ws  = (float*)d_ws;

  float* part = ws;                                    // 512 tiles (8.4 MB)
  float* kv   = ws + (size_t)(N_BATCH * BPB) * 4096;   // 4 tiles
  float* P    = ws;                                    // aliases consumed part

  k1_mfma<<<N_BATCH * BPB, 512, 0, stream>>>(key_mem, val_mem, part);
  k2_reduce<<<256, 256, 0, stream>>>(part, kv, BPB);
  k2b_softmax<<<N_BATCH * 64, 64, 0, stream>>>(kv, P);
  k3_out<<<N_BATCH * (N_TOK / 64), 256, 0, stream>>>(P, key_cur, val_cur,
                                                     alpha, out);
}